// Round 12
// baseline (274.883 us; speedup 1.0000x reference)
//
#include <hip/hip_runtime.h>
#include <hip/hip_fp16.h>

// GCN 3-layer: x -> GCNConv(W1)+BN+ReLU -> GCNConv(W2)+BN+ReLU -> GCNConv(W3)
// CSR built once: 1 u64 atomic/edge -> {count, weighted-degree, in-bucket rank},
// atomic-free fill; edge record u32 {src:16 | norm fixed 2^-15:16}.
// k_mega: interleaved roles (blockIdx parity) -- deg atomics co-resident with
// GEMM1 MFMA from dispatch 0 (R9 range-split serialized; R10 grid.sync 3x worse).
// GEMMs: MFMA f16 16x16x32, fp32 accum, LDS-staged epilogue writing a
// 4-shard (F=96, 48B rows) / 2-shard (F=64, 64B rows) feature layout.
// Aggregation: shard = blockIdx & (S-1) -> power-of-2 shard count pins each
// 2.4-3.2MB slice to a fixed XCD subset (slice < 4MB L2); thread=(node,16B
// chunk) keeps 3-4 consecutive lanes per source row. Synthesis of R8's
// lessons: pinning cut FETCH 4x, but 1-lane rows (64 line-touches/instr)
// lost 2x; 3-lane runs bound that to ~26.

constexpr float BN_EPS = 1e-5f;
constexpr float FIXED_SCALE = 33554432.0f;        // 2^25 (weighted degree accum)
constexpr float INV_FIXED_SCALE = 1.0f / 33554432.0f;
constexpr float NORM_SCALE = 32768.0f;            // 2^15 (edge norm quant)
constexpr float INV_NORM_SCALE = 1.0f / 32768.0f;

typedef _Float16 f16x8 __attribute__((ext_vector_type(8)));
typedef float f32x4 __attribute__((ext_vector_type(4)));

// ---------------- MFMA GEMM block (64 nodes x F), LDS-staged shard epilogue ----
// A: lane loads X[n0+(lane&15)][kt*32+(lane>>4)*8..+7]; C/D: col=lane&15 (f),
// row=(lane>>4)*4+reg (node). LDS row stride padded (104/72 halves) so the
// 4-row MFMA write stride is not 0 mod 32 banks.

template <int K, int F, bool F32X, bool F32W>
__device__ __forceinline__ void gemm_block(const void* __restrict__ Xin,
                                           const void* __restrict__ Win,
                                           _Float16* __restrict__ Y,
                                           int n0b, int tid, int n,
                                           _Float16* lds) {
    constexpr int KT = K / 32;
    constexpr int FT = F / 16;
    constexpr int LROW = (F == 96) ? 104 : 72;   // padded halves per row
    constexpr int CPS = (F == 96) ? 3 : 4;       // uint4 chunks per shard row
    constexpr int SHW = (F == 96) ? 24 : 32;     // halves per shard row
    int wave = tid >> 6;
    int lane = tid & 63;
    int quad = lane >> 4;
    int r = lane & 15;
    int n0 = n0b + wave * 16;
    bool active = (n0 < n);   // N % 16 == 0 -> active waves fully in-bounds

    if (active) {
        f16x8 a[KT];
        if (F32X) {
            const float* xr = (const float*)Xin + (size_t)(n0 + r) * K + quad * 8;
#pragma unroll
            for (int kt = 0; kt < KT; ++kt) {
                float4 v0 = *(const float4*)(xr + kt * 32);
                float4 v1 = *(const float4*)(xr + kt * 32 + 4);
                f16x8 t = {(_Float16)v0.x, (_Float16)v0.y, (_Float16)v0.z, (_Float16)v0.w,
                           (_Float16)v1.x, (_Float16)v1.y, (_Float16)v1.z, (_Float16)v1.w};
                a[kt] = t;
            }
        } else {
            const f16x8* xr = (const f16x8*)((const _Float16*)Xin + (size_t)(n0 + r) * K + quad * 8);
#pragma unroll
            for (int kt = 0; kt < KT; ++kt) a[kt] = xr[kt * 4];
        }

        f32x4 acc[FT];
#pragma unroll
        for (int ft = 0; ft < FT; ++ft) acc[ft] = (f32x4){0.f, 0.f, 0.f, 0.f};

#pragma unroll
        for (int kt = 0; kt < KT; ++kt) {
#pragma unroll
            for (int ft = 0; ft < FT; ++ft) {
                f16x8 b;
                if (F32W) {
                    const float* wr = (const float*)Win + (size_t)(ft * 16 + r) * K + kt * 32 + quad * 8;
                    float4 v0 = *(const float4*)wr;
                    float4 v1 = *(const float4*)(wr + 4);
                    f16x8 t = {(_Float16)v0.x, (_Float16)v0.y, (_Float16)v0.z, (_Float16)v0.w,
                               (_Float16)v1.x, (_Float16)v1.y, (_Float16)v1.z, (_Float16)v1.w};
                    b = t;
                } else {
                    b = *(const f16x8*)((const _Float16*)Win + (size_t)(ft * 16 + r) * K + kt * 32 + quad * 8);
                }
                acc[ft] = __builtin_amdgcn_mfma_f32_16x16x32_f16(a[kt], b, acc[ft], 0, 0, 0);
            }
        }

#pragma unroll
        for (int ft = 0; ft < FT; ++ft) {
#pragma unroll
            for (int reg = 0; reg < 4; ++reg) {
                int lr = wave * 16 + quad * 4 + reg;
                lds[(size_t)lr * LROW + ft * 16 + r] = (_Float16)acc[ft][reg];
            }
        }
    }
    __syncthreads();

    constexpr int CPR = F / 8;            // uint4 chunks per node row
    constexpr int TOTAL = 64 * CPR;
    for (int i = tid; i < TOTAL; i += 256) {
        int row = i / CPR, c = i - row * CPR;
        int s = c / CPS, off = c - s * CPS;
        int grow = n0b + row;
        if (grow < n)
            *(uint4*)(Y + ((size_t)s * n + grow) * SHW + off * 8) =
                *(const uint4*)(lds + (size_t)row * LROW + c * 8);
    }
}

template <int K, int F>
__global__ __launch_bounds__(256) void k_gemm(const _Float16* __restrict__ X,
                                              const _Float16* __restrict__ Wh,
                                              _Float16* __restrict__ Y, int n) {
    __shared__ _Float16 lds[64 * 104];
    gemm_block<K, F, false, false>(X, Wh, Y, blockIdx.x * 64, threadIdx.x, n, lds);
}

// ---------------- mega: interleaved deg atomics | GEMM1 | W2/W3 convert -------

__global__ __launch_bounds__(256) void k_mega(
    const int* __restrict__ col_idx, const float* __restrict__ ew,
    unsigned long long* packed, int* rank, int e_cnt, int pair_b,
    const float* __restrict__ x, const float* __restrict__ W1,
    _Float16* __restrict__ bufA, int n,
    const float* __restrict__ W2, const float* __restrict__ W3,
    _Float16* __restrict__ w2h, _Float16* __restrict__ w3h,
    int w2n4, int w3n4) {
    __shared__ _Float16 lds[64 * 104];
    int b = blockIdx.x;
    if (b < 2 * pair_b) {
        int q = b >> 1;
        if ((b & 1) == 0) {
            // deg role: 1024 edges per block (4 independent atomics/thread)
#pragma unroll
            for (int j = 0; j < 4; ++j) {
                int e = q * 1024 + j * 256 + (int)threadIdx.x;
                if (e < e_cnt) {
                    int c = col_idx[e];
                    unsigned wfix = (unsigned)(ew[e] * FIXED_SCALE + 0.5f);
                    unsigned long long inc = (1ull << 32) | (unsigned long long)wfix;
                    unsigned long long old = atomicAdd(&packed[c], inc);
                    rank[e] = (int)(old >> 32);
                }
            }
        } else {
            gemm_block<128, 96, true, true>(x, W1, bufA, q * 64, threadIdx.x, n, lds);
        }
    } else {
        // convert role: W2|W3 fp32->fp16
        int i = (b - 2 * pair_b) * 256 + (int)threadIdx.x;
        const float* src; _Float16* dst; int o;
        if (i < w2n4) { src = W2; dst = w2h; o = i; }
        else if (i < w2n4 + w3n4) { src = W3; dst = w3h; o = i - w2n4; }
        else return;
        float4 v = ((const float4*)src)[o];
        __half2 h0 = __floats2half2_rn(v.x, v.y);
        __half2 h1 = __floats2half2_rn(v.z, v.w);
        *(uint2*)(dst + (size_t)o * 4) = make_uint2(*(unsigned*)&h0, *(unsigned*)&h1);
    }
}

// ---------------- scans ----------------

__global__ void k_scan1(const unsigned long long* __restrict__ packed,
                        int* bsum, float* dis, int n) {
    __shared__ int s[256];
    int i = blockIdx.x * 256 + threadIdx.x;
    int cnt = 0;
    if (i < n) {
        unsigned long long p = packed[i];
        cnt = (int)(p >> 32);
        float wsum = (float)(unsigned)(p & 0xffffffffull) * INV_FIXED_SCALE;
        dis[i] = rsqrtf(1.0f + wsum);   // self-loop weight 1 included
    }
    s[threadIdx.x] = cnt;
    __syncthreads();
    for (int off = 128; off > 0; off >>= 1) {
        if ((int)threadIdx.x < off) s[threadIdx.x] += s[threadIdx.x + off];
        __syncthreads();
    }
    if (threadIdx.x == 0) bsum[blockIdx.x] = s[0];
}

// each block re-scans the stripe sums + local scan -> row_ptr (nb <= 256)
__global__ void k_scan23(const unsigned long long* __restrict__ packed,
                         const int* __restrict__ bsum,
                         int* row_ptr, int n, int e_total, int nb) {
    __shared__ int sb[256];
    __shared__ int s[256];
    int t = threadIdx.x;
    int bv = (t < nb) ? bsum[t] : 0;
    sb[t] = bv;
    __syncthreads();
    for (int off = 1; off < 256; off <<= 1) {
        int x = (t >= off) ? sb[t - off] : 0;
        __syncthreads();
        sb[t] += x;
        __syncthreads();
    }
    int boff = (blockIdx.x == 0) ? 0 : sb[blockIdx.x - 1];

    int i = blockIdx.x * 256 + t;
    int v = (i < n) ? (int)(packed[i] >> 32) : 0;
    s[t] = v;
    __syncthreads();
    for (int off = 1; off < 256; off <<= 1) {
        int x = (t >= off) ? s[t - off] : 0;
        __syncthreads();
        s[t] += x;
        __syncthreads();
    }
    int ex = s[t] - v + boff;
    if (i < n) row_ptr[i] = ex;
    if (i == 0) row_ptr[n] = e_total;
}

// atomic-free fill: slot = row_ptr[dest] + rank; record = {src:16 | norm:16}
__global__ void k_fill(const int* __restrict__ row_idx, const int* __restrict__ col_idx,
                       const float* __restrict__ ew, const float* __restrict__ dis,
                       const int* __restrict__ row_ptr, const int* __restrict__ rank,
                       unsigned* ep, int e_cnt) {
    int e = blockIdx.x * 256 + threadIdx.x;
    if (e < e_cnt) {
        int r = row_idx[e];
        int c = col_idx[e];
        float nm = dis[r] * ew[e] * dis[c];
        unsigned q = (unsigned)(nm * NORM_SCALE + 0.5f);
        if (q > 65535u) q = 65535u;
        ep[row_ptr[c] + rank[e]] = ((unsigned)r << 16) | q;
    }
}

// ---------------- aggregation over L2-pinned shards ----------------
// shard = blockIdx & (S-1); thread = (node, 16B chunk within shard).

__device__ inline void cvt8(uint4 u, float* f) {
    float2 t;
    t = __half22float2(*(const __half2*)&u.x); f[0] = t.x; f[1] = t.y;
    t = __half22float2(*(const __half2*)&u.y); f[2] = t.x; f[3] = t.y;
    t = __half22float2(*(const __half2*)&u.z); f[4] = t.x; f[5] = t.y;
    t = __half22float2(*(const __half2*)&u.w); f[6] = t.x; f[7] = t.y;
}

__device__ inline void h8_acc(uint4 u, float w, float acc[8]) {
    float2 a = __half22float2(*(const __half2*)&u.x);
    float2 b = __half22float2(*(const __half2*)&u.y);
    float2 c = __half22float2(*(const __half2*)&u.z);
    float2 d = __half22float2(*(const __half2*)&u.w);
    acc[0] = fmaf(w, a.x, acc[0]); acc[1] = fmaf(w, a.y, acc[1]);
    acc[2] = fmaf(w, b.x, acc[2]); acc[3] = fmaf(w, b.y, acc[3]);
    acc[4] = fmaf(w, c.x, acc[4]); acc[5] = fmaf(w, c.y, acc[5]);
    acc[6] = fmaf(w, d.x, acc[6]); acc[7] = fmaf(w, d.y, acc[7]);
}

template <int F, bool BN, bool F32OUT>
__global__ __launch_bounds__(256) void k_aggr(
    const _Float16* __restrict__ xw, const int* __restrict__ row_ptr,
    const unsigned* __restrict__ ep,
    const float* __restrict__ dis, const float* __restrict__ bias,
    const float* __restrict__ g, const float* __restrict__ beta,
    const float* __restrict__ m, const float* __restrict__ v,
    void* __restrict__ out, int n) {
    constexpr int S   = (F == 96) ? 4 : 2;   // shards (power of 2 -> XCD pinning)
    constexpr int CPS = (F == 96) ? 3 : 4;   // uint4 chunks per shard row
    constexpr int SHW = (F == 96) ? 24 : 32; // halves per shard row
    constexpr int SH  = (F == 96) ? 2 : 1;   // log2 S
    int sb = blockIdx.x & (S - 1);
    int idx = ((int)blockIdx.x >> SH) * 256 + (int)threadIdx.x;
    int node = idx / CPS;
    int c = idx - node * CPS;
    if (node >= n) return;

    const uint4* __restrict__ base = (const uint4*)(xw + (size_t)sb * n * SHW);

    float acc[8];
    {
        float d = dis[node];
        float d2 = d * d;
        uint4 sv = base[(size_t)node * CPS + c];
        float t[8];
        cvt8(sv, t);
#pragma unroll
        for (int j = 0; j < 8; ++j) acc[j] = d2 * t[j];
    }

    int e0 = row_ptr[node], e1 = row_ptr[node + 1];
    int e = e0;
    for (; e + 4 <= e1; e += 4) {
        unsigned p0 = ep[e + 0], p1 = ep[e + 1], p2 = ep[e + 2], p3 = ep[e + 3];
        uint4 x0 = base[(size_t)(p0 >> 16) * CPS + c];
        uint4 x1 = base[(size_t)(p1 >> 16) * CPS + c];
        uint4 x2 = base[(size_t)(p2 >> 16) * CPS + c];
        uint4 x3 = base[(size_t)(p3 >> 16) * CPS + c];
        h8_acc(x0, (float)(p0 & 0xffffu) * INV_NORM_SCALE, acc);
        h8_acc(x1, (float)(p1 & 0xffffu) * INV_NORM_SCALE, acc);
        h8_acc(x2, (float)(p2 & 0xffffu) * INV_NORM_SCALE, acc);
        h8_acc(x3, (float)(p3 & 0xffffu) * INV_NORM_SCALE, acc);
    }
    for (; e < e1; ++e) {
        unsigned p = ep[e];
        uint4 xv = base[(size_t)(p >> 16) * CPS + c];
        h8_acc(xv, (float)(p & 0xffffu) * INV_NORM_SCALE, acc);
    }

    int fb = sb * SHW + c * 8;   // global feature base of this chunk
    const float4* bb = (const float4*)(bias + fb);
    float4 b0 = bb[0], b1 = bb[1];
    acc[0] += b0.x; acc[1] += b0.y; acc[2] += b0.z; acc[3] += b0.w;
    acc[4] += b1.x; acc[5] += b1.y; acc[6] += b1.z; acc[7] += b1.w;
    if (BN) {
#pragma unroll
        for (int j = 0; j < 8; ++j) {
            acc[j] = fmaxf((acc[j] - m[fb + j]) * rsqrtf(v[fb + j] + BN_EPS) * g[fb + j]
                           + beta[fb + j], 0.f);
        }
    }
    if (F32OUT) {
        float* op = (float*)out + (size_t)node * F + fb;
        *(float4*)(op + 0) = make_float4(acc[0], acc[1], acc[2], acc[3]);
        *(float4*)(op + 4) = make_float4(acc[4], acc[5], acc[6], acc[7]);
    } else {
        // row-major fp16 for the next GEMM
        __half2 h0 = __floats2half2_rn(acc[0], acc[1]);
        __half2 h1 = __floats2half2_rn(acc[2], acc[3]);
        __half2 h2 = __floats2half2_rn(acc[4], acc[5]);
        __half2 h3 = __floats2half2_rn(acc[6], acc[7]);
        uint4 u = make_uint4(*(unsigned*)&h0, *(unsigned*)&h1,
                             *(unsigned*)&h2, *(unsigned*)&h3);
        *(uint4*)((_Float16*)out + (size_t)node * F + fb) = u;
    }
}

// ---------------- launch ----------------

extern "C" void kernel_launch(void* const* d_in, const int* in_sizes, int n_in,
                              void* d_out, int out_size, void* d_ws, size_t ws_size,
                              hipStream_t stream) {
    constexpr int IN = 128, H = 96, OUT = 64;

    const float* x   = (const float*)d_in[0];
    const int*   ei  = (const int*)d_in[1];
    const float* ew  = (const float*)d_in[2];
    const float* W1  = (const float*)d_in[3];
    const float* b1  = (const float*)d_in[4];
    const float* W2  = (const float*)d_in[5];
    const float* b2  = (const float*)d_in[6];
    const float* W3  = (const float*)d_in[7];
    const float* b3  = (const float*)d_in[8];
    const float* g1  = (const float*)d_in[9];
    const float* be1 = (const float*)d_in[10];
    const float* m1  = (const float*)d_in[11];
    const float* v1  = (const float*)d_in[12];
    const float* g2  = (const float*)d_in[13];
    const float* be2 = (const float*)d_in[14];
    const float* m2  = (const float*)d_in[15];
    const float* v2  = (const float*)d_in[16];

    const int N = in_sizes[0] / IN;   // 50000
    const int E = in_sizes[2];        // 800000
    const int* row_idx = ei;
    const int* col_idx = ei + E;

    char* ws = (char*)d_ws;
    size_t off = 0;
    auto alloc = [&](size_t bytes) -> void* {
        void* p = ws + off;
        off = (off + bytes + 255) & ~(size_t)255;
        return p;
    };
    unsigned long long* packed = (unsigned long long*)alloc((size_t)N * 8);
    float*     dis     = (float*)alloc((size_t)N * 4);
    int*       row_ptr = (int*)alloc((size_t)(N + 1) * 4);
    int*       bsum    = (int*)alloc(256 * 4);
    int*       rank    = (int*)alloc((size_t)E * 4);
    unsigned*  ep      = (unsigned*)alloc((size_t)E * 4);
    _Float16*  w2h     = (_Float16*)alloc((size_t)H * H * 2);
    _Float16*  w3h     = (_Float16*)alloc((size_t)OUT * H * 2);
    _Float16*  bufA    = (_Float16*)alloc((size_t)N * H * 2);   // gemm out (shards)
    _Float16*  bufB    = (_Float16*)alloc((size_t)N * H * 2);   // aggr out (row-major)
    (void)ws_size; (void)n_in; (void)out_size;

    constexpr int W2N4 = H * H / 4, W3N4 = OUT * H / 4;   // 2304 + 1536 = 3840
    const int NB = (N + 255) / 256;          // 196 (<= 256 for scans)
    const int DEG1024 = (E + 1023) / 1024;   // 782
    const int GG = (N / 16 + 3) / 4;         // 782: 64 nodes/block
    const int PAIR = (DEG1024 > GG) ? DEG1024 : GG;   // 782
    const int CVT_B = (W2N4 + W3N4 + 255) / 256;      // 15

    hipMemsetAsync(packed, 0, (size_t)N * 8, stream);
    k_mega<<<2 * PAIR + CVT_B, 256, 0, stream>>>(
        col_idx, ew, packed, rank, E, PAIR,
        x, W1, bufA, N, W2, W3, w2h, w3h, W2N4, W3N4);
    k_scan1<<<NB, 256, 0, stream>>>(packed, bsum, dis, N);
    k_scan23<<<NB, 256, 0, stream>>>(packed, bsum, row_ptr, N, E, NB);
    k_fill<<<(E + 255) / 256, 256, 0, stream>>>(row_idx, col_idx, ew, dis,
                                                row_ptr, rank, ep, E);

    // aggr grids: per-shard threads = N * CPS; shard = blockIdx & (S-1)
    const int GA96 = 4 * ((N * 3 + 255) / 256);   // 4 shards x 586
    const int GA64 = 2 * ((N * 4 + 255) / 256);   // 2 shards x 782

    // layer 1 aggregation (gemm1 ran inside k_mega)
    k_aggr<H, true, false><<<GA96, 256, 0, stream>>>(
        bufA, row_ptr, ep, dis, b1, g1, be1, m1, v1, bufB, N);

    // layer 2
    k_gemm<H, H><<<GG, 256, 0, stream>>>(bufB, w2h, bufA, N);
    k_aggr<H, true, false><<<GA96, 256, 0, stream>>>(
        bufA, row_ptr, ep, dis, b2, g2, be2, m2, v2, bufB, N);

    // layer 3
    k_gemm<H, OUT><<<GG, 256, 0, stream>>>(bufB, w3h, bufA, N);
    k_aggr<OUT, false, true><<<GA64, 256, 0, stream>>>(
        bufA, row_ptr, ep, dis, b3, nullptr, nullptr, nullptr, nullptr, d_out, N);
}

// Round 13
// 264.657 us; speedup vs baseline: 1.0386x; 1.0386x over previous
//
#include <hip/hip_runtime.h>
#include <hip/hip_fp16.h>

// GCN 3-layer: x -> GCNConv(W1)+BN+ReLU -> GCNConv(W2)+BN+ReLU -> GCNConv(W3)
// CSR built once: 1 u64 atomic/edge -> {count, weighted-degree, in-bucket rank},
// atomic-free fill; edge record u32 {src:16 | norm fixed 2^-15:16}.
// k_mega: INTERLEAVED roles (blockIdx parity) so deg-atomic blocks and GEMM1
// MFMA blocks are co-resident from dispatch 0 -- the GEMM runs under the
// ~35us atomic wall (R9's range-split serialized them; R10's cooperative
// grid.sync version was 3x slower; grid-wide barriers are ~100us-class).
// GEMMs: MFMA f16 16x16x32, wave = 16 nodes x F, fp32 accum, LDS-staged
// coalesced uint4 epilogue.
// Aggregation: thread = (node, 16B chunk) -> 12 lanes share one 192B row
// (~2 line-touches/edge, minimal). Feature-shard L2-pinning tested 3x
// (R5/R8/R12): always net-negative vs the x8 XCD refetch -- row-major wins.

constexpr float BN_EPS = 1e-5f;
constexpr float FIXED_SCALE = 33554432.0f;        // 2^25 (weighted degree accum)
constexpr float INV_FIXED_SCALE = 1.0f / 33554432.0f;
constexpr float NORM_SCALE = 32768.0f;            // 2^15 (edge norm quant)
constexpr float INV_NORM_SCALE = 1.0f / 32768.0f;

typedef _Float16 f16x8 __attribute__((ext_vector_type(8)));
typedef float f32x4 __attribute__((ext_vector_type(4)));

// ---------------- MFMA GEMM block (64 nodes x F), LDS-staged epilogue ----------
// A: lane loads X[n0+(lane&15)][kt*32+(lane>>4)*8..+7]; C/D: col=lane&15 (f),
// row=(lane>>4)*4+reg (node). LDS row stride padded so 4-row stride is not
// 0 mod 32 banks (104 halves = 52 dw, 4*52=208 % 32 = 16; 72 -> 144 % 32 = 16).

template <int K, int F, bool F32X, bool F32W>
__device__ __forceinline__ void gemm_block(const void* __restrict__ Xin,
                                           const void* __restrict__ Win,
                                           _Float16* __restrict__ Y,
                                           int n0b, int tid, int n,
                                           _Float16* lds) {
    constexpr int KT = K / 32;
    constexpr int FT = F / 16;
    constexpr int LROW = (F == 96) ? 104 : 72;   // padded halves per row
    int wave = tid >> 6;
    int lane = tid & 63;
    int quad = lane >> 4;
    int r = lane & 15;
    int n0 = n0b + wave * 16;
    bool active = (n0 < n);   // N % 16 == 0, so active waves are fully in-bounds

    if (active) {
        f16x8 a[KT];
        if (F32X) {
            const float* xr = (const float*)Xin + (size_t)(n0 + r) * K + quad * 8;
#pragma unroll
            for (int kt = 0; kt < KT; ++kt) {
                float4 v0 = *(const float4*)(xr + kt * 32);
                float4 v1 = *(const float4*)(xr + kt * 32 + 4);
                f16x8 t = {(_Float16)v0.x, (_Float16)v0.y, (_Float16)v0.z, (_Float16)v0.w,
                           (_Float16)v1.x, (_Float16)v1.y, (_Float16)v1.z, (_Float16)v1.w};
                a[kt] = t;
            }
        } else {
            const f16x8* xr = (const f16x8*)((const _Float16*)Xin + (size_t)(n0 + r) * K + quad * 8);
#pragma unroll
            for (int kt = 0; kt < KT; ++kt) a[kt] = xr[kt * 4];
        }

        f32x4 acc[FT];
#pragma unroll
        for (int ft = 0; ft < FT; ++ft) acc[ft] = (f32x4){0.f, 0.f, 0.f, 0.f};

#pragma unroll
        for (int kt = 0; kt < KT; ++kt) {
#pragma unroll
            for (int ft = 0; ft < FT; ++ft) {
                f16x8 b;
                if (F32W) {
                    const float* wr = (const float*)Win + (size_t)(ft * 16 + r) * K + kt * 32 + quad * 8;
                    float4 v0 = *(const float4*)wr;
                    float4 v1 = *(const float4*)(wr + 4);
                    f16x8 t = {(_Float16)v0.x, (_Float16)v0.y, (_Float16)v0.z, (_Float16)v0.w,
                               (_Float16)v1.x, (_Float16)v1.y, (_Float16)v1.z, (_Float16)v1.w};
                    b = t;
                } else {
                    b = *(const f16x8*)((const _Float16*)Win + (size_t)(ft * 16 + r) * K + kt * 32 + quad * 8);
                }
                acc[ft] = __builtin_amdgcn_mfma_f32_16x16x32_f16(a[kt], b, acc[ft], 0, 0, 0);
            }
        }

#pragma unroll
        for (int ft = 0; ft < FT; ++ft) {
#pragma unroll
            for (int reg = 0; reg < 4; ++reg) {
                int lr = wave * 16 + quad * 4 + reg;
                lds[(size_t)lr * LROW + ft * 16 + r] = (_Float16)acc[ft][reg];
            }
        }
    }
    __syncthreads();

    constexpr int CPR = F / 8;            // uint4 chunks per row
    constexpr int TOTAL = 64 * CPR;
    for (int i = tid; i < TOTAL; i += 256) {
        int row = i / CPR, c = i - row * CPR;
        int grow = n0b + row;
        if (grow < n)
            *(uint4*)(Y + (size_t)grow * F + c * 8) =
                *(const uint4*)(lds + (size_t)row * LROW + c * 8);
    }
}

template <int K, int F>
__global__ __launch_bounds__(256) void k_gemm(const _Float16* __restrict__ X,
                                              const _Float16* __restrict__ Wh,
                                              _Float16* __restrict__ Y, int n) {
    __shared__ _Float16 lds[64 * 104];
    gemm_block<K, F, false, false>(X, Wh, Y, blockIdx.x * 64, threadIdx.x, n, lds);
}

// ---------------- mega: interleaved deg atomics | GEMM1 | W2/W3 convert -------

__global__ __launch_bounds__(256) void k_mega(
    const int* __restrict__ col_idx, const float* __restrict__ ew,
    unsigned long long* packed, int* rank, int e_cnt, int pair_b,
    const float* __restrict__ x, const float* __restrict__ W1,
    _Float16* __restrict__ bufA, int n,
    const float* __restrict__ W2, const float* __restrict__ W3,
    _Float16* __restrict__ w2h, _Float16* __restrict__ w3h,
    int w2n4, int w3n4) {
    __shared__ _Float16 lds[64 * 104];
    int b = blockIdx.x;
    if (b < 2 * pair_b) {
        int q = b >> 1;
        if ((b & 1) == 0) {
            // deg role: 1024 edges per block (4 independent atomics/thread)
#pragma unroll
            for (int j = 0; j < 4; ++j) {
                int e = q * 1024 + j * 256 + (int)threadIdx.x;
                if (e < e_cnt) {
                    int c = col_idx[e];
                    unsigned wfix = (unsigned)(ew[e] * FIXED_SCALE + 0.5f);
                    unsigned long long inc = (1ull << 32) | (unsigned long long)wfix;
                    unsigned long long old = atomicAdd(&packed[c], inc);
                    rank[e] = (int)(old >> 32);
                }
            }
        } else {
            gemm_block<128, 96, true, true>(x, W1, bufA, q * 64, threadIdx.x, n, lds);
        }
    } else {
        // convert role: W2|W3 fp32->fp16, 15 blocks x 256 = 3840 float4 units
        int i = (b - 2 * pair_b) * 256 + (int)threadIdx.x;
        const float* src; _Float16* dst; int o;
        if (i < w2n4) { src = W2; dst = w2h; o = i; }
        else if (i < w2n4 + w3n4) { src = W3; dst = w3h; o = i - w2n4; }
        else return;
        float4 v = ((const float4*)src)[o];
        __half2 h0 = __floats2half2_rn(v.x, v.y);
        __half2 h1 = __floats2half2_rn(v.z, v.w);
        *(uint2*)(dst + (size_t)o * 4) = make_uint2(*(unsigned*)&h0, *(unsigned*)&h1);
    }
}

// ---------------- scans ----------------

__global__ void k_scan1(const unsigned long long* __restrict__ packed,
                        int* bsum, float* dis, int n) {
    __shared__ int s[256];
    int i = blockIdx.x * 256 + threadIdx.x;
    int cnt = 0;
    if (i < n) {
        unsigned long long p = packed[i];
        cnt = (int)(p >> 32);
        float wsum = (float)(unsigned)(p & 0xffffffffull) * INV_FIXED_SCALE;
        dis[i] = rsqrtf(1.0f + wsum);   // self-loop weight 1 included
    }
    s[threadIdx.x] = cnt;
    __syncthreads();
    for (int off = 128; off > 0; off >>= 1) {
        if ((int)threadIdx.x < off) s[threadIdx.x] += s[threadIdx.x + off];
        __syncthreads();
    }
    if (threadIdx.x == 0) bsum[blockIdx.x] = s[0];
}

// each block re-scans the stripe sums + local scan -> row_ptr (nb <= 256)
__global__ void k_scan23(const unsigned long long* __restrict__ packed,
                         const int* __restrict__ bsum,
                         int* row_ptr, int n, int e_total, int nb) {
    __shared__ int sb[256];
    __shared__ int s[256];
    int t = threadIdx.x;
    int bv = (t < nb) ? bsum[t] : 0;
    sb[t] = bv;
    __syncthreads();
    for (int off = 1; off < 256; off <<= 1) {
        int x = (t >= off) ? sb[t - off] : 0;
        __syncthreads();
        sb[t] += x;
        __syncthreads();
    }
    int boff = (blockIdx.x == 0) ? 0 : sb[blockIdx.x - 1];

    int i = blockIdx.x * 256 + t;
    int v = (i < n) ? (int)(packed[i] >> 32) : 0;
    s[t] = v;
    __syncthreads();
    for (int off = 1; off < 256; off <<= 1) {
        int x = (t >= off) ? s[t - off] : 0;
        __syncthreads();
        s[t] += x;
        __syncthreads();
    }
    int ex = s[t] - v + boff;
    if (i < n) row_ptr[i] = ex;
    if (i == 0) row_ptr[n] = e_total;
}

// atomic-free fill: slot = row_ptr[dest] + rank; record = {src:16 | norm:16}
__global__ void k_fill(const int* __restrict__ row_idx, const int* __restrict__ col_idx,
                       const float* __restrict__ ew, const float* __restrict__ dis,
                       const int* __restrict__ row_ptr, const int* __restrict__ rank,
                       unsigned* ep, int e_cnt) {
    int e = blockIdx.x * 256 + threadIdx.x;
    if (e < e_cnt) {
        int r = row_idx[e];
        int c = col_idx[e];
        float nm = dis[r] * ew[e] * dis[c];
        unsigned q = (unsigned)(nm * NORM_SCALE + 0.5f);
        if (q > 65535u) q = 65535u;
        ep[row_ptr[c] + rank[e]] = ((unsigned)r << 16) | q;
    }
}

// ---------------- aggregation (gather fp16, accumulate fp32) ----------------

__device__ inline void cvt8(uint4 u, float* f) {
    float2 t;
    t = __half22float2(*(const __half2*)&u.x); f[0] = t.x; f[1] = t.y;
    t = __half22float2(*(const __half2*)&u.y); f[2] = t.x; f[3] = t.y;
    t = __half22float2(*(const __half2*)&u.z); f[4] = t.x; f[5] = t.y;
    t = __half22float2(*(const __half2*)&u.w); f[6] = t.x; f[7] = t.y;
}

__device__ inline void h8_acc(uint4 u, float w, float acc[8]) {
    float2 a = __half22float2(*(const __half2*)&u.x);
    float2 b = __half22float2(*(const __half2*)&u.y);
    float2 c = __half22float2(*(const __half2*)&u.z);
    float2 d = __half22float2(*(const __half2*)&u.w);
    acc[0] = fmaf(w, a.x, acc[0]); acc[1] = fmaf(w, a.y, acc[1]);
    acc[2] = fmaf(w, b.x, acc[2]); acc[3] = fmaf(w, b.y, acc[3]);
    acc[4] = fmaf(w, c.x, acc[4]); acc[5] = fmaf(w, c.y, acc[5]);
    acc[6] = fmaf(w, d.x, acc[6]); acc[7] = fmaf(w, d.y, acc[7]);
}

template <int F, bool BN, bool F32OUT>
__global__ __launch_bounds__(256) void k_aggr(
    const _Float16* __restrict__ xw, const int* __restrict__ row_ptr,
    const unsigned* __restrict__ ep,
    const float* __restrict__ dis, const float* __restrict__ bias,
    const float* __restrict__ g, const float* __restrict__ beta,
    const float* __restrict__ m, const float* __restrict__ v,
    void* __restrict__ out, int n) {
    constexpr int FQ = F / 8;      // 16B chunks per row: 12 (F=96) or 8 (F=64)
    int tg = blockIdx.x * 256 + threadIdx.x;
    int node = tg / FQ;
    int q = tg - node * FQ;
    if (node >= n) return;

    const uint4* __restrict__ base = (const uint4*)xw;

    float acc[8];
    {
        float d = dis[node];
        float d2 = d * d;
        uint4 sv = base[(size_t)node * FQ + q];
        float t[8];
        cvt8(sv, t);
#pragma unroll
        for (int j = 0; j < 8; ++j) acc[j] = d2 * t[j];
    }

    int e0 = row_ptr[node], e1 = row_ptr[node + 1];
    int e = e0;
    for (; e + 4 <= e1; e += 4) {
        unsigned p0 = ep[e + 0], p1 = ep[e + 1], p2 = ep[e + 2], p3 = ep[e + 3];
        uint4 x0 = base[(size_t)(p0 >> 16) * FQ + q];
        uint4 x1 = base[(size_t)(p1 >> 16) * FQ + q];
        uint4 x2 = base[(size_t)(p2 >> 16) * FQ + q];
        uint4 x3 = base[(size_t)(p3 >> 16) * FQ + q];
        h8_acc(x0, (float)(p0 & 0xffffu) * INV_NORM_SCALE, acc);
        h8_acc(x1, (float)(p1 & 0xffffu) * INV_NORM_SCALE, acc);
        h8_acc(x2, (float)(p2 & 0xffffu) * INV_NORM_SCALE, acc);
        h8_acc(x3, (float)(p3 & 0xffffu) * INV_NORM_SCALE, acc);
    }
    for (; e < e1; ++e) {
        unsigned p = ep[e];
        uint4 xv = base[(size_t)(p >> 16) * FQ + q];
        h8_acc(xv, (float)(p & 0xffffu) * INV_NORM_SCALE, acc);
    }

    int fb = q * 8;
    const float4* bb = (const float4*)(bias + fb);
    float4 b0 = bb[0], b1 = bb[1];
    acc[0] += b0.x; acc[1] += b0.y; acc[2] += b0.z; acc[3] += b0.w;
    acc[4] += b1.x; acc[5] += b1.y; acc[6] += b1.z; acc[7] += b1.w;
    if (BN) {
#pragma unroll
        for (int j = 0; j < 8; ++j) {
            acc[j] = fmaxf((acc[j] - m[fb + j]) * rsqrtf(v[fb + j] + BN_EPS) * g[fb + j]
                           + beta[fb + j], 0.f);
        }
    }
    if (F32OUT) {
        float* op = (float*)out + (size_t)node * F + fb;
        *(float4*)(op + 0) = make_float4(acc[0], acc[1], acc[2], acc[3]);
        *(float4*)(op + 4) = make_float4(acc[4], acc[5], acc[6], acc[7]);
    } else {
        __half2 h0 = __floats2half2_rn(acc[0], acc[1]);
        __half2 h1 = __floats2half2_rn(acc[2], acc[3]);
        __half2 h2 = __floats2half2_rn(acc[4], acc[5]);
        __half2 h3 = __floats2half2_rn(acc[6], acc[7]);
        uint4 u = make_uint4(*(unsigned*)&h0, *(unsigned*)&h1,
                             *(unsigned*)&h2, *(unsigned*)&h3);
        ((uint4*)out)[(size_t)node * FQ + q] = u;
    }
}

// ---------------- launch ----------------

extern "C" void kernel_launch(void* const* d_in, const int* in_sizes, int n_in,
                              void* d_out, int out_size, void* d_ws, size_t ws_size,
                              hipStream_t stream) {
    constexpr int IN = 128, H = 96, OUT = 64;

    const float* x   = (const float*)d_in[0];
    const int*   ei  = (const int*)d_in[1];
    const float* ew  = (const float*)d_in[2];
    const float* W1  = (const float*)d_in[3];
    const float* b1  = (const float*)d_in[4];
    const float* W2  = (const float*)d_in[5];
    const float* b2  = (const float*)d_in[6];
    const float* W3  = (const float*)d_in[7];
    const float* b3  = (const float*)d_in[8];
    const float* g1  = (const float*)d_in[9];
    const float* be1 = (const float*)d_in[10];
    const float* m1  = (const float*)d_in[11];
    const float* v1  = (const float*)d_in[12];
    const float* g2  = (const float*)d_in[13];
    const float* be2 = (const float*)d_in[14];
    const float* m2  = (const float*)d_in[15];
    const float* v2  = (const float*)d_in[16];

    const int N = in_sizes[0] / IN;   // 50000
    const int E = in_sizes[2];        // 800000
    const int* row_idx = ei;
    const int* col_idx = ei + E;

    char* ws = (char*)d_ws;
    size_t off = 0;
    auto alloc = [&](size_t bytes) -> void* {
        void* p = ws + off;
        off = (off + bytes + 255) & ~(size_t)255;
        return p;
    };
    unsigned long long* packed = (unsigned long long*)alloc((size_t)N * 8);
    float*     dis     = (float*)alloc((size_t)N * 4);
    int*       row_ptr = (int*)alloc((size_t)(N + 1) * 4);
    int*       bsum    = (int*)alloc(256 * 4);
    int*       rank    = (int*)alloc((size_t)E * 4);
    unsigned*  ep      = (unsigned*)alloc((size_t)E * 4);
    _Float16*  w2h     = (_Float16*)alloc((size_t)H * H * 2);
    _Float16*  w3h     = (_Float16*)alloc((size_t)OUT * H * 2);
    _Float16*  bufA    = (_Float16*)alloc((size_t)N * H * 2);   // gemm out
    _Float16*  bufB    = (_Float16*)alloc((size_t)N * H * 2);   // aggr out
    (void)ws_size; (void)n_in; (void)out_size;

    constexpr int W2N4 = H * H / 4, W3N4 = OUT * H / 4;   // 2304 + 1536 = 3840
    const int NB = (N + 255) / 256;          // 196 (<= 256 for scans)
    const int DEG1024 = (E + 1023) / 1024;   // 782
    const int GG = (N / 16 + 3) / 4;         // 782: 64 nodes/block
    const int PAIR = (DEG1024 > GG) ? DEG1024 : GG;   // 782
    const int CVT_B = (W2N4 + W3N4 + 255) / 256;      // 15

    hipMemsetAsync(packed, 0, (size_t)N * 8, stream);
    k_mega<<<2 * PAIR + CVT_B, 256, 0, stream>>>(
        col_idx, ew, packed, rank, E, PAIR,
        x, W1, bufA, N, W2, W3, w2h, w3h, W2N4, W3N4);
    k_scan1<<<NB, 256, 0, stream>>>(packed, bsum, dis, N);
    k_scan23<<<NB, 256, 0, stream>>>(packed, bsum, row_ptr, N, E, NB);
    k_fill<<<(E + 255) / 256, 256, 0, stream>>>(row_idx, col_idx, ew, dis,
                                                row_ptr, rank, ep, E);

    const int GA96 = ((size_t)N * (H / 8) + 255) / 256;
    const int GA64 = ((size_t)N * (OUT / 8) + 255) / 256;

    // layer 1 aggregation (gemm1 ran inside k_mega)
    k_aggr<H, true, false><<<GA96, 256, 0, stream>>>(
        bufA, row_ptr, ep, dis, b1, g1, be1, m1, v1, bufB, N);

    // layer 2
    k_gemm<H, H><<<GG, 256, 0, stream>>>(bufB, w2h, bufA, N);
    k_aggr<H, true, false><<<GA96, 256, 0, stream>>>(
        bufA, row_ptr, ep, dis, b2, g2, be2, m2, v2, bufB, N);

    // layer 3
    k_gemm<H, OUT><<<GG, 256, 0, stream>>>(bufB, w3h, bufA, N);
    k_aggr<OUT, false, true><<<GA64, 256, 0, stream>>>(
        bufA, row_ptr, ep, dis, b3, nullptr, nullptr, nullptr, nullptr, d_out, N);
}